// Round 14
// baseline (172.824 us; speedup 1.0000x reference)
//
#include <hip/hip_runtime.h>
#include <hip/hip_bf16.h>

// Problem constants
#define NB   64
#define NCDD 5
#define NHIS 100
#define ND   256
#define NK   10
#define TLD  23040          // T*L*D = 30*3*256
#define THRESH 0.1f
#define NEG_INF (-3.402823466e38f)
#define NROWS_HIS 6400      // 64*100
#define NROWS_CDD 320       // 64*5

typedef float f32x4 __attribute__((ext_vector_type(4)));
typedef unsigned long long u64;

// ---------------------------------------------------------------------------
// Kernel 1: BYTE-IDENTICAL to R8/R9 (control).
// ---------------------------------------------------------------------------
__global__ __launch_bounds__(256) void proj_norm_all(
    const float* __restrict__ his_repr,
    const float* __restrict__ cdd_repr,
    const float* __restrict__ W,
    const float* __restrict__ bvec,
    float* __restrict__ Yall)
{
    __shared__ float red[4][8];
    const int r0  = blockIdx.x * 8;
    const int tid = threadIdx.x;
    const int sub = tid & 3;
    const int grp = tid >> 2;
    const int wave = tid >> 6, lane = tid & 63;

    const float* __restrict__ X = (r0 < NROWS_HIS)
        ? (his_repr + (size_t)r0 * ND)
        : (cdd_repr + (size_t)(r0 - NROWS_HIS) * ND);

    float acc[4][8];
#pragma unroll
    for (int p = 0; p < 4; ++p)
#pragma unroll
        for (int r = 0; r < 8; ++r) acc[p][r] = 0.f;

#pragma unroll 4
    for (int i = 0; i < 16; ++i) {
        const int kb = sub * 4 + 16 * i;
        float4 x4[8];
#pragma unroll
        for (int r = 0; r < 8; ++r)
            x4[r] = *(const float4*)(X + (size_t)r * ND + kb);
#pragma unroll
        for (int p = 0; p < 4; ++p) {
            const int d = p * 64 + grp;
            const float4 w4 = *(const float4*)(W + (size_t)d * ND + kb);
#pragma unroll
            for (int r = 0; r < 8; ++r)
                acc[p][r] += w4.x * x4[r].x + w4.y * x4[r].y
                           + w4.z * x4[r].z + w4.w * x4[r].w;
        }
    }

#pragma unroll
    for (int p = 0; p < 4; ++p)
#pragma unroll
        for (int r = 0; r < 8; ++r) {
            float v = acc[p][r];
            v += __shfl_xor(v, 1);
            v += __shfl_xor(v, 2);
            acc[p][r] = v;
        }

    float bias[4];
#pragma unroll
    for (int p = 0; p < 4; ++p) bias[p] = bvec[p * 64 + grp];

    float ss[8];
#pragma unroll
    for (int r = 0; r < 8; ++r) {
        float t = 0.f;
#pragma unroll
        for (int p = 0; p < 4; ++p) {
            const float y = acc[p][r] + bias[p];
            acc[p][r] = y;
            t += y * y;
        }
        for (int off = 32; off; off >>= 1) t += __shfl_xor(t, off);
        ss[r] = t;
    }
    if (lane == 0) {
#pragma unroll
        for (int r = 0; r < 8; ++r) red[wave][r] = ss[r];
    }
    __syncthreads();

#pragma unroll
    for (int r = 0; r < 8; ++r) {
        const float s = 0.25f * (red[0][r] + red[1][r] + red[2][r] + red[3][r]);
        const float scale = 1.0f / fmaxf(sqrtf(s), 1e-12f);
        if (sub == 0) {
#pragma unroll
            for (int p = 0; p < 4; ++p)
                Yall[(size_t)(r0 + r) * ND + p * 64 + grp] = acc[p][r] * scale;
        }
    }
}

// ---------------------------------------------------------------------------
// Kernel 2: R8 attn+topk body + dedup-build tail.
// After the 5 top-10s, one thread per block builds the unique-row list and a
// per-unique 64-bit target mask over the 50 (c,k) slots (50 serial iters).
// ---------------------------------------------------------------------------
__global__ __launch_bounds__(512) void attn_topk_kernel(
    const float* __restrict__ cdd_p,
    const float* __restrict__ his_p,
    float* __restrict__ out_idx_f,
    int* __restrict__ ws_idx,
    float* __restrict__ ws_w,
    int* __restrict__ ws_nu,       // [NB]
    int* __restrict__ ws_uidx,     // [NB][50]
    u64* __restrict__ ws_tmask)    // [NB][50]
{
    __shared__ float attn_s[NCDD][128];
    __shared__ int   pick_h[NCDD * NK];
    __shared__ int   map_s[NHIS];
    __shared__ int   uidx_s[NCDD * NK];
    __shared__ u64   tmask_s[NCDD * NK];
    __shared__ int   nu_s;
    const int b   = blockIdx.x;
    const int tid = threadIdx.x;
    const int sub = tid & 3, grp = tid >> 2;
    const int wave = tid >> 6, lane = tid & 63;

    if (tid < NHIS) map_s[tid] = -1;

    const float* __restrict__ cbase = cdd_p + (size_t)b * NCDD * ND;
    const float* __restrict__ hbase = his_p + (size_t)b * NHIS * ND;

#pragma unroll
    for (int it = 0; it < 4; ++it) {
        const int task = it * 128 + grp;
        if (task < NCDD * NHIS) {
            const int c = task / NHIS, h = task - c * NHIS;
            const float* __restrict__ crow = cbase + (size_t)c * ND;
            const float* __restrict__ hrow = hbase + (size_t)h * ND;
            float a = 0.f;
#pragma unroll
            for (int i = 0; i < 16; ++i) {
                const int kb = sub * 4 + 16 * i;
                const float4 cv = *(const float4*)(crow + kb);
                const float4 hv = *(const float4*)(hrow + kb);
                a += cv.x * hv.x + cv.y * hv.y + cv.z * hv.z + cv.w * hv.w;
            }
            a += __shfl_xor(a, 1);
            a += __shfl_xor(a, 2);
            if (sub == 0) attn_s[c][h] = a;
        }
    }
    __syncthreads();

    if (wave < NCDD) {
        const int c = wave;
        float v0 = attn_s[c][lane];
        float v1 = (lane + 64 < NHIS) ? attn_s[c][lane + 64] : NEG_INF;
#pragma unroll
        for (int k = 0; k < NK; ++k) {
            float lv; int li;
            if (v1 > v0) { lv = v1; li = lane + 64; }
            else         { lv = v0; li = lane; }            // tie -> lower idx
            for (int off = 1; off < 64; off <<= 1) {
                const float ov = __shfl_xor(lv, off);
                const int   oi = __shfl_xor(li, off);
                if (ov > lv || (ov == lv && oi < li)) { lv = ov; li = oi; }
            }
            if (lane == 0) {
                const float w = (lv < THRESH) ? 0.0f : lv;
                const int g = (b * NCDD + c) * NK + k;
                ws_idx[g] = li;
                ws_w[g]   = w;
                out_idx_f[g] = (float)li;
                pick_h[c * NK + k] = li;
            }
            if (li == lane)            v0 = NEG_INF;
            else if (li == lane + 64)  v1 = NEG_INF;
        }
    }
    __syncthreads();

    // Dedup build (serial, 50 iterations)
    if (tid == 0) {
        int nu = 0;
        for (int t = 0; t < NCDD * NK; ++t) {
            const int h = pick_h[t];
            int u = map_s[h];
            if (u < 0) {
                u = nu++;
                map_s[h] = u;
                uidx_s[u] = h;
                tmask_s[u] = 0ull;
            }
            tmask_s[u] |= (1ull << t);
        }
        nu_s = nu;
        ws_nu[b] = nu;
    }
    __syncthreads();

    if (tid < NCDD * NK && tid < nu_s) {
        ws_uidx[b * (NCDD * NK) + tid]  = uidx_s[tid];
        ws_tmask[b * (NCDD * NK) + tid] = tmask_s[tid];
    }
}

// ---------------------------------------------------------------------------
// Kernel 3: DEDUP gather. Block (b,u) = u-th unique row of batch b: reads
// the 92KB row ONCE into registers (R9 max-MLP body) and writes every target
// (c,k) output row, each scaled by its own w (w==0 targets get zeros, and
// contribute no read). Cuts duplicate fabric read traversals (~18%).
// XCD-chunked mapping unchanged: XCD x owns b in [8x, 8x+8).
// ---------------------------------------------------------------------------
__global__ __launch_bounds__(256) void gather_dedup(
    const float* __restrict__ his_emb,
    const float* __restrict__ ws_w,
    const int* __restrict__ ws_nu,
    const int* __restrict__ ws_uidx,
    const u64* __restrict__ ws_tmask,
    float* __restrict__ out)
{
    const int orig = blockIdx.x;
    const int m = (orig & 7) * 400 + (orig >> 3);   // XCD-chunked (bijective)
    const int b = m / (NCDD * NK);
    const int u = m - b * (NCDD * NK);
    if (u >= ws_nu[b]) return;

    const int tid = threadIdx.x;
    const int h = ws_uidx[b * (NCDD * NK) + u];
    u64 mask = ws_tmask[b * (NCDD * NK) + u];

    // Does any target need the row data?
    bool anyread = false;
    {
        u64 mm = mask;
        while (mm) {
            const int t = __ffsll(mm) - 1;
            mm &= mm - 1;
            if (ws_w[b * (NCDD * NK) + t] != 0.0f) anyread = true;
        }
    }

    f32x4 v[22];
    f32x4 vt;
    const bool tail = (tid < 128);
    if (anyread) {
        const f32x4* __restrict__ src =
            (const f32x4*)(his_emb + ((size_t)b * NHIS + h) * TLD);
#pragma unroll
        for (int j = 0; j < 22; ++j) v[j] = src[tid + j * 256];
        if (tail) vt = src[22 * 256 + tid];
    }

    while (mask) {
        const int t = __ffsll(mask) - 1;
        mask &= mask - 1;
        const float w = ws_w[b * (NCDD * NK) + t];
        f32x4* __restrict__ dst =
            (f32x4*)(out + (size_t)(b * (NCDD * NK) + t) * TLD);
        if (w == 0.0f) {
            const f32x4 z = {0.f, 0.f, 0.f, 0.f};
#pragma unroll
            for (int j = 0; j < 22; ++j) dst[tid + j * 256] = z;
            if (tail) dst[22 * 256 + tid] = z;
        } else {
#pragma unroll
            for (int j = 0; j < 22; ++j) dst[tid + j * 256] = v[j] * w;
            if (tail) dst[22 * 256 + tid] = vt * w;
        }
    }
}

// ---------------------------------------------------------------------------
extern "C" void kernel_launch(void* const* d_in, const int* in_sizes, int n_in,
                              void* d_out, int out_size, void* d_ws, size_t ws_size,
                              hipStream_t stream)
{
    const float* cdd_repr = (const float*)d_in[0];   // (64,5,256)
    const float* his_repr = (const float*)d_in[1];   // (64,100,256)
    const float* his_emb  = (const float*)d_in[2];   // (64,100,30,3,256)
    const float* W_sel    = (const float*)d_in[3];   // (256,256)
    const float* b_sel    = (const float*)d_in[4];   // (256,)
    float* out = (float*)d_out;

    // Workspace layout
    char* ws = (char*)d_ws;
    float* Yall  = (float*)ws;                       // 6720 rows * 256 * 4 = 6,881,280
    float* his_p = Yall;                             // rows [0, 6400)
    float* cdd_p = Yall + (size_t)NROWS_HIS * ND;    // rows [6400, 6720)
    int*   idx_i = (int*)(ws + 6881280);             // 3200*4
    float* w_w   = (float*)(ws + 6894080);           // 3200*4
    int*   nu_g  = (int*)(ws + 6906880);             // 64*4
    int*   uidx_g= (int*)(ws + 6907136);             // 3200*4
    u64*   tmask_g = (u64*)(ws + 6920064);           // 3200*8 (8-aligned)

    // Output: his_activated [73,728,000] then idx [3200] (as float values)
    float* out_idx_f = out + (size_t)NB * NCDD * NK * TLD;

    proj_norm_all<<<(NROWS_HIS + NROWS_CDD) / 8, 256, 0, stream>>>(
        his_repr, cdd_repr, W_sel, b_sel, Yall);
    attn_topk_kernel<<<NB, 512, 0, stream>>>(cdd_p, his_p, out_idx_f,
                                             idx_i, w_w, nu_g, uidx_g, tmask_g);
    gather_dedup<<<NB * NCDD * NK, 256, 0, stream>>>(his_emb, w_w, nu_g,
                                                     uidx_g, tmask_g, out);
}

// Round 17
// 160.011 us; speedup vs baseline: 1.0801x; 1.0801x over previous
//
#include <hip/hip_runtime.h>
#include <hip/hip_bf16.h>

// Problem constants
#define NB   64
#define NCDD 5
#define NHIS 100
#define ND   256
#define NK   10
#define TLD  23040          // T*L*D = 30*3*256
#define THRESH 0.1f
#define NEG_INF (-3.402823466e38f)
#define NROWS_HIS 6400      // 64*100
#define NROWS_CDD 320       // 64*5

typedef float f32x4 __attribute__((ext_vector_type(4)));

// ---------------------------------------------------------------------------
// Kernel 1: BYTE-IDENTICAL to R9 (proven, part of the 162.3 us best).
// ---------------------------------------------------------------------------
__global__ __launch_bounds__(256) void proj_norm_all(
    const float* __restrict__ his_repr,
    const float* __restrict__ cdd_repr,
    const float* __restrict__ W,
    const float* __restrict__ bvec,
    float* __restrict__ Yall)
{
    __shared__ float red[4][8];
    const int r0  = blockIdx.x * 8;
    const int tid = threadIdx.x;
    const int sub = tid & 3;
    const int grp = tid >> 2;
    const int wave = tid >> 6, lane = tid & 63;

    const float* __restrict__ X = (r0 < NROWS_HIS)
        ? (his_repr + (size_t)r0 * ND)
        : (cdd_repr + (size_t)(r0 - NROWS_HIS) * ND);

    float acc[4][8];
#pragma unroll
    for (int p = 0; p < 4; ++p)
#pragma unroll
        for (int r = 0; r < 8; ++r) acc[p][r] = 0.f;

#pragma unroll 4
    for (int i = 0; i < 16; ++i) {
        const int kb = sub * 4 + 16 * i;
        float4 x4[8];
#pragma unroll
        for (int r = 0; r < 8; ++r)
            x4[r] = *(const float4*)(X + (size_t)r * ND + kb);
#pragma unroll
        for (int p = 0; p < 4; ++p) {
            const int d = p * 64 + grp;
            const float4 w4 = *(const float4*)(W + (size_t)d * ND + kb);
#pragma unroll
            for (int r = 0; r < 8; ++r)
                acc[p][r] += w4.x * x4[r].x + w4.y * x4[r].y
                           + w4.z * x4[r].z + w4.w * x4[r].w;
        }
    }

#pragma unroll
    for (int p = 0; p < 4; ++p)
#pragma unroll
        for (int r = 0; r < 8; ++r) {
            float v = acc[p][r];
            v += __shfl_xor(v, 1);
            v += __shfl_xor(v, 2);
            acc[p][r] = v;
        }

    float bias[4];
#pragma unroll
    for (int p = 0; p < 4; ++p) bias[p] = bvec[p * 64 + grp];

    float ss[8];
#pragma unroll
    for (int r = 0; r < 8; ++r) {
        float t = 0.f;
#pragma unroll
        for (int p = 0; p < 4; ++p) {
            const float y = acc[p][r] + bias[p];
            acc[p][r] = y;
            t += y * y;
        }
        for (int off = 32; off; off >>= 1) t += __shfl_xor(t, off);
        ss[r] = t;
    }
    if (lane == 0) {
#pragma unroll
        for (int r = 0; r < 8; ++r) red[wave][r] = ss[r];
    }
    __syncthreads();

#pragma unroll
    for (int r = 0; r < 8; ++r) {
        const float s = 0.25f * (red[0][r] + red[1][r] + red[2][r] + red[3][r]);
        const float scale = 1.0f / fmaxf(sqrtf(s), 1e-12f);
        if (sub == 0) {
#pragma unroll
            for (int p = 0; p < 4; ++p)
                Yall[(size_t)(r0 + r) * ND + p * 64 + grp] = acc[p][r] * scale;
        }
    }
}

// ---------------------------------------------------------------------------
// Kernel 2: attn + exact top-10 at 320 blocks (one per (b,c)), 256 threads.
// Dot phase is the PROVEN R10 phase-1 code (validated in R10): 4-lane group
// grp handles h=grp and h=grp+64; 2-shfl butterfly. Top-k is the proven
// wave-0 butterfly (lax.top_k: descending, lowest index on ties).
// 5x more blocks than R9's 64-block version -> less latency-bound tail.
// ---------------------------------------------------------------------------
__global__ __launch_bounds__(256) void attn_topk_kernel(
    const float* __restrict__ cdd_p,
    const float* __restrict__ his_p,
    float* __restrict__ out_idx_f,
    int* __restrict__ ws_idx,
    float* __restrict__ ws_w)
{
    __shared__ float attn_s[128];
    const int bc  = blockIdx.x;            // b*NCDD + c
    const int b   = bc / NCDD;
    const int tid = threadIdx.x;
    const int sub = tid & 3, grp = tid >> 2;   // 64 groups
    const int wave = tid >> 6, lane = tid & 63;

    const float* __restrict__ crow = cdd_p + (size_t)bc * ND;
    const float* __restrict__ hbase = his_p + (size_t)b * NHIS * ND;
    {
        const int h0 = grp, h1 = grp + 64;
        const float* __restrict__ h0row = hbase + (size_t)h0 * ND;
        const float* __restrict__ h1row = hbase + (size_t)h1 * ND;
        float a0 = 0.f, a1 = 0.f;
#pragma unroll
        for (int i = 0; i < 16; ++i) {
            const int kb = sub * 4 + 16 * i;
            const float4 cv = *(const float4*)(crow + kb);
            const float4 v0 = *(const float4*)(h0row + kb);
            a0 += cv.x * v0.x + cv.y * v0.y + cv.z * v0.z + cv.w * v0.w;
            if (h1 < NHIS) {
                const float4 v1 = *(const float4*)(h1row + kb);
                a1 += cv.x * v1.x + cv.y * v1.y + cv.z * v1.z + cv.w * v1.w;
            }
        }
        a0 += __shfl_xor(a0, 1); a0 += __shfl_xor(a0, 2);
        a1 += __shfl_xor(a1, 1); a1 += __shfl_xor(a1, 2);
        if (sub == 0) {
            attn_s[h0] = a0;
            if (h1 < NHIS) attn_s[h1] = a1;
        }
    }
    __syncthreads();

    if (wave == 0) {
        float v0 = attn_s[lane];
        float v1 = (lane + 64 < NHIS) ? attn_s[lane + 64] : NEG_INF;
#pragma unroll
        for (int k = 0; k < NK; ++k) {
            float lv; int li;
            if (v1 > v0) { lv = v1; li = lane + 64; }
            else         { lv = v0; li = lane; }            // tie -> lower idx
            for (int off = 1; off < 64; off <<= 1) {
                const float ov = __shfl_xor(lv, off);
                const int   oi = __shfl_xor(li, off);
                if (ov > lv || (ov == lv && oi < li)) { lv = ov; li = oi; }
            }
            if (lane == 0) {
                const float w = (lv < THRESH) ? 0.0f : lv;
                const int g = bc * NK + k;
                ws_idx[g] = li;
                ws_w[g]   = w;
                out_idx_f[g] = (float)li;
            }
            if (li == lane)            v0 = NEG_INF;
            else if (li == lane + 64)  v1 = NEG_INF;
        }
    }
}

// ---------------------------------------------------------------------------
// Kernel 3: gather + scale — BYTE-IDENTICAL to R9 (calibrated ~103 us,
// ~92% of the demonstrated mixed-stream fabric ceiling).
// ---------------------------------------------------------------------------
__global__ __launch_bounds__(256) void gather_kernel(
    const float* __restrict__ his_emb,
    const int* __restrict__ ws_idx,
    const float* __restrict__ ws_w,
    float* __restrict__ out)
{
    const int orig = blockIdx.x;
    const int g = (orig & 7) * 400 + (orig >> 3);   // XCD-chunked (bijective)
    const int b = g / (NCDD * NK);
    const int tid = threadIdx.x;
    const float w = ws_w[g];

    f32x4* __restrict__ dst = (f32x4*)(out + (size_t)g * TLD);

    if (w == 0.0f) {
        const f32x4 z = {0.f, 0.f, 0.f, 0.f};
#pragma unroll
        for (int it = 0; it < 22; ++it) dst[tid + it * 256] = z;
        if (tid < 128) dst[22 * 256 + tid] = z;
        return;
    }

    const int idx = ws_idx[g];
    const f32x4* __restrict__ src =
        (const f32x4*)(his_emb + ((size_t)b * NHIS + idx) * TLD);

    f32x4 v[22];
    f32x4 vt;
#pragma unroll
    for (int j = 0; j < 22; ++j) v[j] = src[tid + j * 256];
    const bool tail = (tid < 128);
    if (tail) vt = src[22 * 256 + tid];

#pragma unroll
    for (int j = 0; j < 22; ++j) dst[tid + j * 256] = v[j] * w;
    if (tail) dst[22 * 256 + tid] = vt * w;
}

// ---------------------------------------------------------------------------
extern "C" void kernel_launch(void* const* d_in, const int* in_sizes, int n_in,
                              void* d_out, int out_size, void* d_ws, size_t ws_size,
                              hipStream_t stream)
{
    const float* cdd_repr = (const float*)d_in[0];   // (64,5,256)
    const float* his_repr = (const float*)d_in[1];   // (64,100,256)
    const float* his_emb  = (const float*)d_in[2];   // (64,100,30,3,256)
    const float* W_sel    = (const float*)d_in[3];   // (256,256)
    const float* b_sel    = (const float*)d_in[4];   // (256,)
    float* out = (float*)d_out;

    // Workspace layout
    char* ws = (char*)d_ws;
    float* Yall  = (float*)ws;                       // 6720 rows * 256 * 4
    float* his_p = Yall;                             // rows [0, 6400)
    float* cdd_p = Yall + (size_t)NROWS_HIS * ND;    // rows [6400, 6720)
    int*   idx_i = (int*)(ws + 6881280);             // 3200*4
    float* w_w   = (float*)(ws + 6894080);           // 3200*4

    // Output: his_activated [73,728,000] then idx [3200] (as float values)
    float* out_idx_f = out + (size_t)NB * NCDD * NK * TLD;

    proj_norm_all<<<(NROWS_HIS + NROWS_CDD) / 8, 256, 0, stream>>>(
        his_repr, cdd_repr, W_sel, b_sel, Yall);
    attn_topk_kernel<<<NB * NCDD, 256, 0, stream>>>(cdd_p, his_p,
                                                    out_idx_f, idx_i, w_w);
    gather_kernel<<<NB * NCDD * NK, 256, 0, stream>>>(his_emb, idx_i, w_w, out);
}